// Round 2
// baseline (34.525 us; speedup 1.0000x reference)
//
#include <hip/hip_runtime.h>

#define NB 16
#define KK 128
#define CC 64

// 2*log2(e): store A2/B2 pre-scaled so tanh(x) = 1 - 2/(exp2(s)+1), s = (a+b) pre-scaled
#define TSCALE 2.8853900817779268f

// Kernel 1: per row r = n*K+k (one wave each, 8 rows / 512-thread block):
//   h      = [t, x_r] @ W_lin + b_lin
//   unary  = tanh(h@W_u1+b_u1)@W_u2 + b_u2
//   A2[r]  = TSCALE*(h @ W_b1[e][0:C] + b_b1[e])   (receiver/j part, e interleaved)
//   B2[r]  = TSCALE*(h @ W_b1[e][C:2C])            (sender/i part,   e interleaved)
// W_b1 (64 KiB) staged in LDS once per block, shared by 8 waves.
__global__ __launch_bounds__(512) void precompute_kernel(
    const float* __restrict__ t, const float* __restrict__ x,
    const float* __restrict__ W_lin, const float* __restrict__ b_lin,
    const float* __restrict__ W_u1, const float* __restrict__ b_u1,
    const float* __restrict__ W_u2, const float* __restrict__ b_u2,
    const float* __restrict__ W_b1, const float* __restrict__ b_b1,
    float* __restrict__ A2, float* __restrict__ B2, float* __restrict__ unary)
{
    __shared__ float Wb1s[2 * 2 * CC * CC];   // 64 KiB, same layout as W_b1 [ET][2C][C]

    const int tid = threadIdx.x;
    {   // stage W_b1: 16384 floats = 4096 float4, 8 per thread
        const float4* src = (const float4*)W_b1;
        float4* dst = (float4*)Wb1s;
#pragma unroll
        for (int it = 0; it < 8; ++it) dst[tid + it * 512] = src[tid + it * 512];
    }
    __syncthreads();

    const int lane = tid & 63;
    const int r    = blockIdx.x * 8 + (tid >> 6);   // row in [0, N*K)

    const float xv = x[r * CC + lane];
    float h = fmaf(t[0], W_lin[lane], b_lin[lane]);
#pragma unroll 8
    for (int k = 0; k < CC; ++k) {
        float xk = __shfl(xv, k);
        h = fmaf(xk, W_lin[(k + 1) * CC + lane], h);
    }

    float u1 = b_u1[lane];
    float a0 = b_b1[lane], a1 = b_b1[CC + lane];
    float bb0 = 0.f, bb1 = 0.f;
#pragma unroll 4
    for (int k = 0; k < CC; ++k) {
        float hk = __shfl(h, k);
        u1  = fmaf(hk, W_u1[k * CC + lane], u1);
        a0  = fmaf(hk, Wb1s[k * CC + lane], a0);
        bb0 = fmaf(hk, Wb1s[(CC + k) * CC + lane], bb0);
        a1  = fmaf(hk, Wb1s[2 * CC * CC + k * CC + lane], a1);
        bb1 = fmaf(hk, Wb1s[2 * CC * CC + (CC + k) * CC + lane], bb1);
    }

    float tu = fmaf(-2.f, __builtin_amdgcn_rcpf(__builtin_amdgcn_exp2f(TSCALE * u1) + 1.f), 1.f);
    float u2 = b_u2[lane];
#pragma unroll 8
    for (int k = 0; k < CC; ++k) {
        float uk = __shfl(tu, k);
        u2 = fmaf(uk, W_u2[k * CC + lane], u2);
    }

    const int idx = r * CC + lane;
    unary[idx] = u2;
    ((float2*)A2)[idx] = make_float2(TSCALE * a0, TSCALE * a1);
    ((float2*)B2)[idx] = make_float2(TSCALE * bb0, TSCALE * bb1);
}

// Kernel 2: one block per (n, j). 4 waves split the i-reduction (32 i each):
//   G[e,h] = sum_i E[n,i,j,e] * tanh-from-prescaled(A[e,n,j,h] + B[e,n,i,h])
//   out[n,j,c] = unary + (1/K) * sum_e (G[e]@W_b2[e] + b_b2[e]*sum_i E)
__global__ __launch_bounds__(256) void binary_kernel(
    const float* __restrict__ E, const float* __restrict__ W_b2,
    const float* __restrict__ b_b2, const float* __restrict__ A2,
    const float* __restrict__ B2, const float* __restrict__ unary,
    float* __restrict__ out)
{
    __shared__ float Gs[4 * CC * 2];    // [w][c][e] partials, 2 KiB
    __shared__ float Ss[4 * 2];         // per-wave sum_i E
    __shared__ float Gred[CC * 2];      // reduced G, [c][e]
    __shared__ float Accs[4 * CC];      // epilogue partials

    const int tid  = threadIdx.x;
    const int lane = tid & 63;
    const int w    = tid >> 6;
    const int b    = blockIdx.x;
    const int n    = b >> 7;
    const int j    = b & 127;
    const int rj   = n * KK + j;

    const float2 a2 = ((const float2*)A2)[rj * CC + lane];
    const float2* B2p = ((const float2*)B2) + (n * KK + w * 32) * CC + lane;
    const float2* Ep  = ((const float2*)E)  + (n * KK + w * 32) * KK + j;

    float G0 = 0.f, G1 = 0.f, S0 = 0.f, S1 = 0.f;
#pragma unroll 8
    for (int i = 0; i < 32; ++i) {
        float2 bb = B2p[i * CC];
        float2 wg = Ep[i * KK];
        float e0 = __builtin_amdgcn_exp2f(a2.x + bb.x);
        float e1 = __builtin_amdgcn_exp2f(a2.y + bb.y);
        float t0 = fmaf(-2.f, __builtin_amdgcn_rcpf(e0 + 1.f), 1.f);
        float t1 = fmaf(-2.f, __builtin_amdgcn_rcpf(e1 + 1.f), 1.f);
        G0 = fmaf(wg.x, t0, G0);
        G1 = fmaf(wg.y, t1, G1);
        S0 += wg.x;
        S1 += wg.y;
    }
    ((float2*)Gs)[w * CC + lane] = make_float2(G0, G1);
    if (lane == 0) ((float2*)Ss)[w] = make_float2(S0, S1);
    __syncthreads();

    // reduce 4 wave-partials of G into Gred (128 floats, interleaved [c][e])
    if (tid < 128) Gred[tid] = Gs[tid] + Gs[128 + tid] + Gs[256 + tid] + Gs[384 + tid];
    __syncthreads();

    const float2 s0 = ((const float2*)Ss)[0], s1 = ((const float2*)Ss)[1];
    const float2 s2 = ((const float2*)Ss)[2], s3 = ((const float2*)Ss)[3];
    const float St0 = s0.x + s1.x + s2.x + s3.x;
    const float St1 = s0.y + s1.y + s2.y + s3.y;

    // epilogue matvec, h-range split across waves; lane = output channel c
    float acc = 0.f;
#pragma unroll
    for (int hi = 0; hi < 16; ++hi) {
        const int hh = w * 16 + hi;
        float2 g = ((const float2*)Gred)[hh];
        acc = fmaf(g.x, W_b2[hh * CC + lane], acc);
        acc = fmaf(g.y, W_b2[CC * CC + hh * CC + lane], acc);
    }
    Accs[w * CC + lane] = acc;
    __syncthreads();

    if (w == 0) {
        float a = Accs[lane] + Accs[CC + lane] + Accs[2 * CC + lane] + Accs[3 * CC + lane];
        a += b_b2[lane] * St0 + b_b2[CC + lane] * St1;
        out[rj * CC + lane] = unary[rj * CC + lane] + a * (1.f / 128.f);
    }
}

extern "C" void kernel_launch(void* const* d_in, const int* in_sizes, int n_in,
                              void* d_out, int out_size, void* d_ws, size_t ws_size,
                              hipStream_t stream) {
    const float* t     = (const float*)d_in[0];
    const float* x     = (const float*)d_in[1];
    const float* E     = (const float*)d_in[2];
    const float* W_lin = (const float*)d_in[3];
    const float* b_lin = (const float*)d_in[4];
    const float* W_u1  = (const float*)d_in[5];
    const float* b_u1  = (const float*)d_in[6];
    const float* W_u2  = (const float*)d_in[7];
    const float* b_u2  = (const float*)d_in[8];
    const float* W_b1  = (const float*)d_in[9];
    const float* b_b1  = (const float*)d_in[10];
    const float* W_b2  = (const float*)d_in[11];
    const float* b_b2  = (const float*)d_in[12];
    float* out = (float*)d_out;

    float* ws    = (float*)d_ws;
    float* A2    = ws;                 // 2*N*K*C floats (e-interleaved, TSCALE-prescaled)
    float* B2    = ws + 2 * NB * KK * CC;
    float* unary = ws + 4 * NB * KK * CC;

    precompute_kernel<<<NB * KK / 8, 512, 0, stream>>>(
        t, x, W_lin, b_lin, W_u1, b_u1, W_u2, b_u2, W_b1, b_b1, A2, B2, unary);
    binary_kernel<<<NB * KK, 256, 0, stream>>>(
        E, W_b2, b_b2, A2, B2, unary, out);
}